// Round 1
// baseline (997.816 us; speedup 1.0000x reference)
//
#include <hip/hip_runtime.h>
#include <math.h>

// ChildSumTreeLSTM, round 6.
// Round-5 structure + T3/T4 prefetch pipeline: all GEMM kernels now
// double-buffer LDS and issue next K-segment's global_load_lds BEFORE
// computing the current segment. Raw s_barrier + manual vmcnt(0) AFTER
// compute (never a drain between issue and compute) hides HBM latency
// under MFMA. LDS 2x (72 KB big / 56 KB small+leaf) -> 2 blocks/CU.

#define Bb 8
#define Lleaf 16384
#define Nn 32767
#define Dd 256

typedef __attribute__((ext_vector_type(8))) short short8;
typedef __attribute__((ext_vector_type(4))) float float4v;

__device__ __forceinline__ float sigf(float x) {
    return __builtin_amdgcn_rcpf(1.0f + __expf(-x));
}
__device__ __forceinline__ float tanh_fast(float x) {
    return fmaf(2.0f, sigf(2.0f * x), -1.0f);
}
__device__ __forceinline__ unsigned short f2bf(float f) {
    unsigned int u = __float_as_uint(f);
    u = (u + 0x7FFFu + ((u >> 16) & 1u)) >> 16;   // RTNE, finite inputs
    return (unsigned short)u;
}
__device__ __forceinline__ float bf2f(unsigned short h) {
    return __uint_as_float(((unsigned int)h) << 16);
}
__device__ __forceinline__ void load_lds16(const void* g, void* l) {
    __builtin_amdgcn_global_load_lds(
        (const __attribute__((address_space(1))) unsigned int*)g,
        (__attribute__((address_space(3))) unsigned int*)l, 16, 0, 0);
}

// ---------------- x fp32 -> bf16 (identity layout, all nodes) --------------
__global__ __launch_bounds__(256) void xcast(
    const float* __restrict__ x, unsigned short* __restrict__ xbf)
{
    const int base = (blockIdx.x * 256 + threadIdx.x) * 8;   // < 8*Nn*256
    const float4* p = (const float4*)(x + base);
    const float4 f0 = p[0], f1 = p[1];
    union { unsigned short us[8]; uint4 v; } pk;
    pk.us[0] = f2bf(f0.x); pk.us[1] = f2bf(f0.y);
    pk.us[2] = f2bf(f0.z); pk.us[3] = f2bf(f0.w);
    pk.us[4] = f2bf(f1.x); pk.us[5] = f2bf(f1.y);
    pk.us[6] = f2bf(f1.z); pk.us[7] = f2bf(f1.w);
    *(uint4*)(xbf + base) = pk.v;
}

// ---------------- weight packing (once per call, ~2 MB) --------------------
__global__ __launch_bounds__(256) void pack_internal(
    const float* __restrict__ W_iou, const float* __restrict__ U_iou,
    const float* __restrict__ W_f,   const float* __restrict__ U_f,
    unsigned short* __restrict__ Bt)
{
    const int idx = blockIdx.x * 256 + threadIdx.x;      // < 1280*768
    const int col = idx / 768, k = idx - col * 768;
    const int q = col / 80, rem = col - q * 80;
    const int g = rem >> 4, r = rem & 15;
    const int d = (q << 4) + r;
    const int seg = k >> 8, kk = k & 255;
    float val;
    if (g < 3) {
        val = (seg == 0) ? W_iou[kk * 768 + g * 256 + d]
                         : U_iou[kk * 768 + g * 256 + d];
    } else if (seg == 0) {
        val = W_f[kk * 256 + d];
    } else if (seg == 1) {
        val = (g == 3) ? U_f[kk * 256 + d] : 0.0f;
    } else {
        val = (g == 4) ? U_f[kk * 256 + d] : 0.0f;
    }
    Bt[idx] = f2bf(val);
}

__global__ __launch_bounds__(256) void pack_leaf(
    const float* __restrict__ W_iou, unsigned short* __restrict__ Btl)
{
    const int idx = blockIdx.x * 256 + threadIdx.x;      // < 768*256
    const int col = idx >> 8, k = idx & 255;
    const int q = col / 48, rem = col - q * 48;
    const int g = rem >> 4, r = rem & 15;
    const int d = (q << 4) + r;
    Btl[idx] = f2bf(W_iou[k * 768 + g * 256 + d]);
}

// ---------------- big internal levels (n >= 128): uniform batch ------------
// 1D grid: (B*n/128)*8; bx = idx>>3, by = idx&7.
__global__ __launch_bounds__(256, 2) void gemm_level_big(
    const unsigned short* __restrict__ xbf, const unsigned short* __restrict__ Bt,
    const float* __restrict__ b_iou, const float* __restrict__ b_f,
    unsigned short* __restrict__ h_out, float* __restrict__ c_out,
    const unsigned short* __restrict__ h_ch, const float* __restrict__ c_ch,
    int n, int lvl)
{
    __shared__ unsigned short Alds[2][128 * 64];   // 2 x 16 KB, swizzled
    __shared__ unsigned short Blds[2][160 * 64];   // 2 x 20 KB, swizzled
    const int tid  = threadIdx.x;
    const int wave = tid >> 6, lane = tid & 63;
    const int l16  = lane & 15, q4 = lane >> 4;
    const int bx   = blockIdx.x >> 3, by = blockIdx.x & 7;
    const int m0   = bx * 128;
    const int n0   = by * 160;
    const int lr   = lane >> 3;                 // row-in-group 0..7
    const int lp   = (lane & 7) ^ lr;           // swizzled k-part

    // whole tile in one batch (n >= 128); heap x-node of row m0+r = xr0 + r
    const int b   = m0 >> lvl;
    const int xr0 = m0 + (n - 1) + b * (Nn - n);

    auto stageA = [&](int kk, unsigned short* dst) {
        #pragma unroll
        for (int it = 0; it < 4; ++it) {
            const int g = it * 4 + wave;       // 0..15
            const int r = g * 8 + lr;
            const unsigned short* src;
            if (kk < 4) {
                src = xbf + (((xr0 + r) << 8) + kk * 64 + lp * 8);
            } else {
                const int sel = (kk >= 8) ? 1 : 0;
                src = h_ch + (((2 * (m0 + r) + sel) << 8) + ((kk - 4) & 3) * 64 + lp * 8);
            }
            load_lds16(src, dst + g * 512);
        }
    };
    auto stageB = [&](int kk, unsigned short* dst) {
        #pragma unroll
        for (int it = 0; it < 5; ++it) {
            const int g = it * 4 + wave;       // 0..19
            const int row = g * 8 + lr;
            load_lds16(Bt + ((n0 + row) * 768 + kk * 64 + lp * 8), dst + g * 512);
        }
    };

    unsigned short* Ac = Alds[0]; unsigned short* An = Alds[1];
    unsigned short* Bc = Blds[0]; unsigned short* Bn = Blds[1];

    // issue first stage immediately; bias loads overlap its latency
    stageA(0, Ac); stageB(0, Bc);

    float4v acc[2][10];
    #pragma unroll
    for (int qq = 0; qq < 2; ++qq) {
        const int d = ((by * 2 + qq) << 4) + l16;
        float bv0 = b_iou[d], bv1 = b_iou[256 + d], bv2 = b_iou[512 + d];
        float bv3 = b_f[d];
        float bv[5] = {bv0, bv1, bv2, bv3, bv3};
        #pragma unroll
        for (int g = 0; g < 5; ++g) {
            float4v v; v[0] = bv[g]; v[1] = bv[g]; v[2] = bv[g]; v[3] = bv[g];
            acc[0][qq * 5 + g] = v; acc[1][qq * 5 + g] = v;
        }
    }

    asm volatile("s_waitcnt vmcnt(0)" ::: "memory");
    __builtin_amdgcn_s_barrier();

    for (int kk = 0; kk < 12; ++kk) {          // segs: 0-3 x, 4-7 h1, 8-11 h2
        if (kk < 11) { stageA(kk + 1, An); stageB(kk + 1, Bn); }
        #pragma unroll
        for (int ks = 0; ks < 2; ++ks) {
            const int pa = ks * 4 + q4;
            const int sw = (pa ^ (l16 & 7)) * 8;
            const short8 a0 = *(const short8*)&Ac[(wave * 32 + l16) * 64 + sw];
            const short8 a1 = *(const short8*)&Ac[(wave * 32 + 16 + l16) * 64 + sw];
            #pragma unroll
            for (int ni = 0; ni < 10; ++ni) {
                const short8 bf = *(const short8*)&Bc[(ni * 16 + l16) * 64 + sw];
                acc[0][ni] = __builtin_amdgcn_mfma_f32_16x16x32_bf16(a0, bf, acc[0][ni], 0, 0, 0);
                acc[1][ni] = __builtin_amdgcn_mfma_f32_16x16x32_bf16(a1, bf, acc[1][ni], 0, 0, 0);
            }
        }
        if (kk < 11) {
            asm volatile("s_waitcnt vmcnt(0)" ::: "memory");
            __builtin_amdgcn_s_barrier();
            unsigned short* t = Ac; Ac = An; An = t;
            t = Bc; Bc = Bn; Bn = t;
        }
    }

    #pragma unroll
    for (int mi = 0; mi < 2; ++mi) {
        #pragma unroll
        for (int reg = 0; reg < 4; ++reg) {
            const int row_l = wave * 32 + mi * 16 + (q4 << 2) + reg;
            const int m = m0 + row_l;
            const int cbase = (2 * m) << 8;
            const int obase = m << 8;
            #pragma unroll
            for (int qq = 0; qq < 2; ++qq) {
                const int d = ((by * 2 + qq) << 4) + l16;
                const float i_ = acc[mi][qq * 5 + 0][reg];
                const float o_ = acc[mi][qq * 5 + 1][reg];
                const float u_ = acc[mi][qq * 5 + 2][reg];
                const float f1 = acc[mi][qq * 5 + 3][reg];
                const float f2 = acc[mi][qq * 5 + 4][reg];
                const float c1 = c_ch[cbase + d];
                const float c2 = c_ch[cbase + 256 + d];
                const float c = sigf(i_) * tanh_fast(u_) + sigf(f1) * c1 + sigf(f2) * c2;
                const float h = sigf(o_) * tanh_fast(c);
                c_out[obase + d] = c;
                h_out[obase + d] = f2bf(h);
            }
        }
    }
}

// ---------------- generic internal level (lvl 6..4) ------------------------
__global__ __launch_bounds__(256, 2) void gemm_level(
    const unsigned short* __restrict__ xbf, const unsigned short* __restrict__ Bt,
    const float* __restrict__ b_iou, const float* __restrict__ b_f,
    unsigned short* __restrict__ h_out, float* __restrict__ c_out,
    const unsigned short* __restrict__ h_ch, const float* __restrict__ c_ch,
    int n, int lvl)
{
    __shared__ unsigned short Alds[2][128 * 64];
    __shared__ unsigned short Blds[2][160 * 64];
    const int tid  = threadIdx.x;
    const int wave = tid >> 6, lane = tid & 63;
    const int l16  = lane & 15, q4 = lane >> 4;
    const int m0   = blockIdx.x * 128;
    const int n0   = blockIdx.y * 160;
    const int lr   = lane >> 3;
    const int lp   = (lane & 7) ^ lr;

    auto stageA = [&](int kk, unsigned short* dst) {
        #pragma unroll
        for (int it = 0; it < 4; ++it) {
            const int g = it * 4 + wave;
            const int r = g * 8 + lr;
            const int m = m0 + r;
            const unsigned short* src;
            if (kk < 4) {
                const int bb = m >> lvl;
                src = xbf + (((m + (n - 1) + bb * (Nn - n)) << 8) + kk * 64 + lp * 8);
            } else {
                const int sel = (kk >= 8) ? 1 : 0;
                src = h_ch + (((2 * m + sel) << 8) + ((kk - 4) & 3) * 64 + lp * 8);
            }
            load_lds16(src, dst + g * 512);
        }
    };
    auto stageB = [&](int kk, unsigned short* dst) {
        #pragma unroll
        for (int it = 0; it < 5; ++it) {
            const int g = it * 4 + wave;
            const int row = g * 8 + lr;
            load_lds16(Bt + ((n0 + row) * 768 + kk * 64 + lp * 8), dst + g * 512);
        }
    };

    unsigned short* Ac = Alds[0]; unsigned short* An = Alds[1];
    unsigned short* Bc = Blds[0]; unsigned short* Bn = Blds[1];

    stageA(0, Ac); stageB(0, Bc);

    float4v acc[2][10];
    #pragma unroll
    for (int qq = 0; qq < 2; ++qq) {
        const int d = ((blockIdx.y * 2 + qq) << 4) + l16;
        float bv0 = b_iou[d], bv1 = b_iou[256 + d], bv2 = b_iou[512 + d];
        float bv3 = b_f[d];
        float bv[5] = {bv0, bv1, bv2, bv3, bv3};
        #pragma unroll
        for (int g = 0; g < 5; ++g) {
            float4v v; v[0] = bv[g]; v[1] = bv[g]; v[2] = bv[g]; v[3] = bv[g];
            acc[0][qq * 5 + g] = v; acc[1][qq * 5 + g] = v;
        }
    }

    asm volatile("s_waitcnt vmcnt(0)" ::: "memory");
    __builtin_amdgcn_s_barrier();

    for (int kk = 0; kk < 12; ++kk) {
        if (kk < 11) { stageA(kk + 1, An); stageB(kk + 1, Bn); }
        #pragma unroll
        for (int ks = 0; ks < 2; ++ks) {
            const int pa = ks * 4 + q4;
            const int sw = (pa ^ (l16 & 7)) * 8;
            const short8 a0 = *(const short8*)&Ac[(wave * 32 + l16) * 64 + sw];
            const short8 a1 = *(const short8*)&Ac[(wave * 32 + 16 + l16) * 64 + sw];
            #pragma unroll
            for (int ni = 0; ni < 10; ++ni) {
                const short8 bf = *(const short8*)&Bc[(ni * 16 + l16) * 64 + sw];
                acc[0][ni] = __builtin_amdgcn_mfma_f32_16x16x32_bf16(a0, bf, acc[0][ni], 0, 0, 0);
                acc[1][ni] = __builtin_amdgcn_mfma_f32_16x16x32_bf16(a1, bf, acc[1][ni], 0, 0, 0);
            }
        }
        if (kk < 11) {
            asm volatile("s_waitcnt vmcnt(0)" ::: "memory");
            __builtin_amdgcn_s_barrier();
            unsigned short* t = Ac; Ac = An; An = t;
            t = Bc; Bc = Bn; Bn = t;
        }
    }

    #pragma unroll
    for (int mi = 0; mi < 2; ++mi) {
        #pragma unroll
        for (int reg = 0; reg < 4; ++reg) {
            const int row_l = wave * 32 + mi * 16 + (q4 << 2) + reg;
            const int m = m0 + row_l;
            const int cbase = (2 * m) << 8;
            const int obase = m << 8;
            #pragma unroll
            for (int qq = 0; qq < 2; ++qq) {
                const int d = ((blockIdx.y * 2 + qq) << 4) + l16;
                const float i_ = acc[mi][qq * 5 + 0][reg];
                const float o_ = acc[mi][qq * 5 + 1][reg];
                const float u_ = acc[mi][qq * 5 + 2][reg];
                const float f1 = acc[mi][qq * 5 + 3][reg];
                const float f2 = acc[mi][qq * 5 + 4][reg];
                const float c1 = c_ch[cbase + d];
                const float c2 = c_ch[cbase + 256 + d];
                const float c = sigf(i_) * tanh_fast(u_) + sigf(f1) * c1 + sigf(f2) * c2;
                const float h = sigf(o_) * tanh_fast(c);
                c_out[obase + d] = c;
                h_out[obase + d] = f2bf(h);
            }
        }
    }
}

// ---------------- tiny levels (n <= 8): M=64 MFMA, clamp+guard -------------
__global__ __launch_bounds__(256, 2) void gemm_small(
    const unsigned short* __restrict__ xbf, const unsigned short* __restrict__ Bt,
    const float* __restrict__ b_iou, const float* __restrict__ b_f,
    unsigned short* __restrict__ h_out, float* __restrict__ c_out,
    const unsigned short* __restrict__ h_ch, const float* __restrict__ c_ch,
    int n, int lvl)
{
    __shared__ unsigned short Alds[2][64 * 64];    // 2 x 8 KB
    __shared__ unsigned short Blds[2][160 * 64];   // 2 x 20 KB
    const int tid  = threadIdx.x;
    const int wave = tid >> 6, lane = tid & 63;
    const int l16  = lane & 15, q4 = lane >> 4;
    const int n0   = blockIdx.y * 160;
    const int lr   = lane >> 3;
    const int lp   = (lane & 7) ^ lr;
    const int rmax = 8 * n - 1;

    auto stageA = [&](int kk, unsigned short* dst) {
        #pragma unroll
        for (int it = 0; it < 2; ++it) {        // stage A: 8 row-groups
            const int g = it * 4 + wave;       // 0..7
            const int r = g * 8 + lr;
            const int m = (r > rmax) ? rmax : r;
            const unsigned short* src;
            if (kk < 4) {
                const int bb = m >> lvl;
                src = xbf + (((m + (n - 1) + bb * (Nn - n)) << 8) + kk * 64 + lp * 8);
            } else {
                const int sel = (kk >= 8) ? 1 : 0;
                src = h_ch + (((2 * m + sel) << 8) + ((kk - 4) & 3) * 64 + lp * 8);
            }
            load_lds16(src, dst + g * 512);
        }
    };
    auto stageB = [&](int kk, unsigned short* dst) {
        #pragma unroll
        for (int it = 0; it < 5; ++it) {
            const int g = it * 4 + wave;
            const int row = g * 8 + lr;
            load_lds16(Bt + ((n0 + row) * 768 + kk * 64 + lp * 8), dst + g * 512);
        }
    };

    unsigned short* Ac = Alds[0]; unsigned short* An = Alds[1];
    unsigned short* Bc = Blds[0]; unsigned short* Bn = Blds[1];

    stageA(0, Ac); stageB(0, Bc);

    float4v acc[10];
    #pragma unroll
    for (int qq = 0; qq < 2; ++qq) {
        const int d = ((blockIdx.y * 2 + qq) << 4) + l16;
        float bv0 = b_iou[d], bv1 = b_iou[256 + d], bv2 = b_iou[512 + d];
        float bv3 = b_f[d];
        float bv[5] = {bv0, bv1, bv2, bv3, bv3};
        #pragma unroll
        for (int g = 0; g < 5; ++g) {
            float4v v; v[0] = bv[g]; v[1] = bv[g]; v[2] = bv[g]; v[3] = bv[g];
            acc[qq * 5 + g] = v;
        }
    }

    asm volatile("s_waitcnt vmcnt(0)" ::: "memory");
    __builtin_amdgcn_s_barrier();

    for (int kk = 0; kk < 12; ++kk) {
        if (kk < 11) { stageA(kk + 1, An); stageB(kk + 1, Bn); }
        #pragma unroll
        for (int ks = 0; ks < 2; ++ks) {
            const int pa = ks * 4 + q4;
            const int sw = (pa ^ (l16 & 7)) * 8;
            const short8 a0 = *(const short8*)&Ac[(wave * 16 + l16) * 64 + sw];
            #pragma unroll
            for (int ni = 0; ni < 10; ++ni) {
                const short8 bf = *(const short8*)&Bc[(ni * 16 + l16) * 64 + sw];
                acc[ni] = __builtin_amdgcn_mfma_f32_16x16x32_bf16(a0, bf, acc[ni], 0, 0, 0);
            }
        }
        if (kk < 11) {
            asm volatile("s_waitcnt vmcnt(0)" ::: "memory");
            __builtin_amdgcn_s_barrier();
            unsigned short* t = Ac; Ac = An; An = t;
            t = Bc; Bc = Bn; Bn = t;
        }
    }

    #pragma unroll
    for (int reg = 0; reg < 4; ++reg) {
        const int row_l = wave * 16 + (q4 << 2) + reg;
        const int m = (row_l > rmax) ? rmax : row_l;
        const bool valid = (row_l <= rmax);
        const int cbase = (2 * m) << 8;
        const int obase = m << 8;
        #pragma unroll
        for (int qq = 0; qq < 2; ++qq) {
            const int d = ((blockIdx.y * 2 + qq) << 4) + l16;
            const float i_ = acc[qq * 5 + 0][reg];
            const float o_ = acc[qq * 5 + 1][reg];
            const float u_ = acc[qq * 5 + 2][reg];
            const float f1 = acc[qq * 5 + 3][reg];
            const float f2 = acc[qq * 5 + 4][reg];
            const float c1 = c_ch[cbase + d];
            const float c2 = c_ch[cbase + 256 + d];
            const float c = sigf(i_) * tanh_fast(u_) + sigf(f1) * c1 + sigf(f2) * c2;
            const float h = sigf(o_) * tanh_fast(c);
            if (valid) {
                c_out[obase + d] = c;
                h_out[obase + d] = f2bf(h);
            }
        }
    }
}

// ---------------- leaf MFMA GEMM -------------------------------------------
// 1D grid (1024*8); tile M=128, N=96, K=256, BK=64; A via global_load_lds.
__global__ __launch_bounds__(256, 2) void gemm_leaf(
    const unsigned short* __restrict__ xbf, const unsigned short* __restrict__ Btl,
    const float* __restrict__ b_iou,
    unsigned short* __restrict__ h_out, float* __restrict__ c_out)
{
    __shared__ unsigned short Alds[2][128 * 64];   // 2 x 16 KB
    __shared__ unsigned short Blds[2][96 * 64];    // 2 x 12 KB
    const int tid  = threadIdx.x;
    const int wave = tid >> 6, lane = tid & 63;
    const int l16  = lane & 15, q4 = lane >> 4;
    const int bx   = blockIdx.x >> 3, by = blockIdx.x & 7;
    const int m0   = bx * 128;
    const int n0   = by * 96;
    const int lr   = lane >> 3;
    const int lp   = (lane & 7) ^ lr;

    const int b   = m0 >> 14;
    const int xr0 = m0 + (Lleaf - 1) + b * (Nn - Lleaf);

    auto stageA = [&](int kk, unsigned short* dst) {
        #pragma unroll
        for (int it = 0; it < 4; ++it) {        // 16 row-groups
            const int g = it * 4 + wave;
            const int r = g * 8 + lr;
            load_lds16(xbf + (((xr0 + r) << 8) + kk * 64 + lp * 8), dst + g * 512);
        }
    };
    auto stageB = [&](int kk, unsigned short* dst) {
        #pragma unroll
        for (int it = 0; it < 3; ++it) {        // 12 row-groups
            const int g = it * 4 + wave;        // 0..11
            const int row = g * 8 + lr;
            load_lds16(Btl + ((n0 + row) * 256 + kk * 64 + lp * 8), dst + g * 512);
        }
    };

    unsigned short* Ac = Alds[0]; unsigned short* An = Alds[1];
    unsigned short* Bc = Blds[0]; unsigned short* Bn = Blds[1];

    stageA(0, Ac); stageB(0, Bc);

    float4v acc[2][6];
    #pragma unroll
    for (int qq = 0; qq < 2; ++qq) {
        const int d = ((by * 2 + qq) << 4) + l16;
        float bv[3] = {b_iou[d], b_iou[256 + d], b_iou[512 + d]};
        #pragma unroll
        for (int g = 0; g < 3; ++g) {
            float4v v; v[0] = bv[g]; v[1] = bv[g]; v[2] = bv[g]; v[3] = bv[g];
            acc[0][qq * 3 + g] = v; acc[1][qq * 3 + g] = v;
        }
    }

    asm volatile("s_waitcnt vmcnt(0)" ::: "memory");
    __builtin_amdgcn_s_barrier();

    for (int kk = 0; kk < 4; ++kk) {
        if (kk < 3) { stageA(kk + 1, An); stageB(kk + 1, Bn); }
        #pragma unroll
        for (int ks = 0; ks < 2; ++ks) {
            const int pa = ks * 4 + q4;
            const int sw = (pa ^ (l16 & 7)) * 8;
            const short8 a0 = *(const short8*)&Ac[(wave * 32 + l16) * 64 + sw];
            const short8 a1 = *(const short8*)&Ac[(wave * 32 + 16 + l16) * 64 + sw];
            #pragma unroll
            for (int ni = 0; ni < 6; ++ni) {
                const short8 bf = *(const short8*)&Bc[(ni * 16 + l16) * 64 + sw];
                acc[0][ni] = __builtin_amdgcn_mfma_f32_16x16x32_bf16(a0, bf, acc[0][ni], 0, 0, 0);
                acc[1][ni] = __builtin_amdgcn_mfma_f32_16x16x32_bf16(a1, bf, acc[1][ni], 0, 0, 0);
            }
        }
        if (kk < 3) {
            asm volatile("s_waitcnt vmcnt(0)" ::: "memory");
            __builtin_amdgcn_s_barrier();
            unsigned short* t = Ac; Ac = An; An = t;
            t = Bc; Bc = Bn; Bn = t;
        }
    }

    #pragma unroll
    for (int mi = 0; mi < 2; ++mi) {
        #pragma unroll
        for (int reg = 0; reg < 4; ++reg) {
            const int row_l = wave * 32 + mi * 16 + (q4 << 2) + reg;
            const int obase = (m0 + row_l) << 8;
            #pragma unroll
            for (int qq = 0; qq < 2; ++qq) {
                const int d = ((by * 2 + qq) << 4) + l16;
                const float i_ = acc[mi][qq * 3 + 0][reg];
                const float o_ = acc[mi][qq * 3 + 1][reg];
                const float u_ = acc[mi][qq * 3 + 2][reg];
                const float c = sigf(i_) * tanh_fast(u_);
                const float h = sigf(o_) * tanh_fast(c);
                c_out[obase + d] = c;
                h_out[obase + d] = f2bf(h);
            }
        }
    }
}

__global__ __launch_bounds__(256) void out_kernel(
    const unsigned short* __restrict__ h_root, const float* __restrict__ c_root,
    float* __restrict__ out)
{
    const int t = threadIdx.x;
    const int b = blockIdx.x;
    out[b * 512 + t]       = bf2f(h_root[(b << 8) + t]);   // root row = b
    out[b * 512 + 256 + t] = c_root[(b << 8) + t];
}

extern "C" void kernel_launch(void* const* d_in, const int* in_sizes, int n_in,
                              void* d_out, int out_size, void* d_ws, size_t ws_size,
                              hipStream_t stream) {
    const float* x     = (const float*)d_in[0];
    const float* W_iou = (const float*)d_in[1];
    const float* b_iou = (const float*)d_in[2];
    const float* U_iou = (const float*)d_in[3];
    const float* W_f   = (const float*)d_in[4];
    const float* b_f   = (const float*)d_in[5];
    const float* U_f   = (const float*)d_in[6];
    float* out = (float*)d_out;

    // arenas: E = even levels (leaf=14,12,..,0) rows B*16384; O = odd, B*8192
    char* p = (char*)d_ws;
    unsigned short* xbf = (unsigned short*)p;  p += (size_t)Bb * Nn * Dd * 2;       // 134 MB
    float* cE = (float*)p;                     p += (size_t)Bb * Lleaf * Dd * 4;    // 134 MB
    float* cO = (float*)p;                     p += (size_t)Bb * (Lleaf/2) * Dd * 4;// 67 MB
    unsigned short* hE = (unsigned short*)p;   p += (size_t)Bb * Lleaf * Dd * 2;    // 67 MB
    unsigned short* hO = (unsigned short*)p;   p += (size_t)Bb * (Lleaf/2) * Dd * 2;// 33.5 MB
    unsigned short* Bt  = (unsigned short*)p;  p += 1280 * 768 * 2;
    unsigned short* Btl = (unsigned short*)p;

    xcast<<<(Bb * Nn * Dd) / (256 * 8), 256, 0, stream>>>(x, xbf);
    pack_internal<<<(1280 * 768) / 256, 256, 0, stream>>>(W_iou, U_iou, W_f, U_f, Bt);
    pack_leaf<<<(768 * 256) / 256, 256, 0, stream>>>(W_iou, Btl);

    // leaf (lvl 14, even) -> E
    gemm_leaf<<<(Bb * Lleaf / 128) * 8, 256, 0, stream>>>(xbf, Btl, b_iou, hE, cE);

    for (int lvl = 13; lvl >= 7; --lvl) {                   // n = 8192 .. 128
        const int n = 1 << lvl;
        unsigned short* ho = (lvl & 1) ? hO : hE;  float* co = (lvl & 1) ? cO : cE;
        unsigned short* hc = (lvl & 1) ? hE : hO;  float* cc = (lvl & 1) ? cE : cO;
        gemm_level_big<<<(Bb * n / 128) * 8, 256, 0, stream>>>(
            xbf, Bt, b_iou, b_f, ho, co, hc, cc, n, lvl);
    }
    for (int lvl = 6; lvl >= 4; --lvl) {                    // n = 64, 32, 16
        const int n = 1 << lvl;
        unsigned short* ho = (lvl & 1) ? hO : hE;  float* co = (lvl & 1) ? cO : cE;
        unsigned short* hc = (lvl & 1) ? hE : hO;  float* cc = (lvl & 1) ? cE : cO;
        gemm_level<<<dim3(Bb * n / 128, 8), 256, 0, stream>>>(
            xbf, Bt, b_iou, b_f, ho, co, hc, cc, n, lvl);
    }
    for (int lvl = 3; lvl >= 0; --lvl) {                    // n = 8 .. 1
        const int n = 1 << lvl;
        unsigned short* ho = (lvl & 1) ? hO : hE;  float* co = (lvl & 1) ? cO : cE;
        unsigned short* hc = (lvl & 1) ? hE : hO;  float* cc = (lvl & 1) ? cE : cO;
        gemm_small<<<dim3(1, 8), 256, 0, stream>>>(
            xbf, Bt, b_iou, b_f, ho, co, hc, cc, n, lvl);
    }
    out_kernel<<<Bb, 256, 0, stream>>>(hE, cE, out);        // lvl 0 is even
}